// Round 3
// baseline (666.202 us; speedup 1.0000x reference)
//
#include <hip/hip_runtime.h>

#define T_LEN 3000
#define TQ 750      // T/4 float4 chunks
#define C_CH 8

// One wave (64 lanes) per (b,f) slice. Lanes stride over T in float4 steps.
// 64 accumulators/lane: [0..7] diag re, [8..35] offdiag re, [36..63] offdiag im.
// Pair index p = 7c - c(c-1)/2 + (e-c-1) for c<e.
// Output: REAL plane (B,F,C,C) float32. (Harness drops imag of complex64.)
// If out_size shows room for an imag plane, it is written planar after real.
__global__ void psd_kernel(const float* __restrict__ Xr,
                           const float* __restrict__ Xi,
                           const float* __restrict__ Mk,
                           float* __restrict__ out,
                           int real_elems, int write_imag) {
    const int slice = blockIdx.x;
    const int lane  = threadIdx.x;

    const float4* xr4 = reinterpret_cast<const float4*>(Xr) + (size_t)slice * (C_CH * TQ);
    const float4* xi4 = reinterpret_cast<const float4*>(Xi) + (size_t)slice * (C_CH * TQ);
    const float4* mk4 = reinterpret_cast<const float4*>(Mk) + (size_t)slice * TQ;

    // ---- Phase 1: mask sum over T (wave butterfly reduce) ----
    float s = 0.f;
    for (int q = lane; q < TQ; q += 64) {
        float4 v = mk4[q];
        s += (v.x + v.y) + (v.z + v.w);
    }
#pragma unroll
    for (int off = 32; off > 0; off >>= 1) s += __shfl_xor(s, off);
    const float inv = 1.0f / (s + 1e-15f);

    // ---- Phase 2: accumulate Hermitian PSD ----
    float acc[64];
#pragma unroll
    for (int k = 0; k < 64; ++k) acc[k] = 0.f;

    for (int q = lane; q < TQ; q += 64) {
        float4 mv = mk4[q];   // 12KB slice re-read: L1-resident
        float mm[4] = {mv.x * inv, mv.y * inv, mv.z * inv, mv.w * inv};
        float ar[C_CH][4], ai[C_CH][4];
#pragma unroll
        for (int c = 0; c < C_CH; ++c) {
            float4 v = xr4[c * TQ + q];
            ar[c][0] = v.x; ar[c][1] = v.y; ar[c][2] = v.z; ar[c][3] = v.w;
            float4 w = xi4[c * TQ + q];
            ai[c][0] = w.x; ai[c][1] = w.y; ai[c][2] = w.z; ai[c][3] = w.w;
        }
#pragma unroll
        for (int j = 0; j < 4; ++j) {
            const float m = mm[j];
            float mr[C_CH], mi[C_CH];
#pragma unroll
            for (int c = 0; c < C_CH; ++c) {
                mr[c] = m * ar[c][j];
                mi[c] = m * ai[c][j];
            }
            // diagonal: re = m*(xr^2 + xi^2)
#pragma unroll
            for (int c = 0; c < C_CH; ++c)
                acc[c] += mr[c] * ar[c][j] + mi[c] * ai[c][j];
            // upper triangle: psd[c][e] = sum m * X[c] * conj(X[e])
#pragma unroll
            for (int c = 0; c < C_CH; ++c) {
#pragma unroll
                for (int e = c + 1; e < C_CH; ++e) {
                    const int p = 7 * c - (c * (c - 1)) / 2 + (e - c - 1);
                    acc[8 + p]  += mr[c] * ar[e][j] + mi[c] * ai[e][j];
                    acc[36 + p] += mi[c] * ar[e][j] - mr[c] * ai[e][j];
                }
            }
        }
    }

    // ---- Epilogue: cross-lane transpose-reduce in LDS ----
    // stride 65: write bank = (65*l + k)%32 = (l+k)%32 -> 2 lanes/bank (free)
    __shared__ float lds[64 * 65 + 128];
    float* fin = lds + 64 * 65;   // [0..63] real plane (c*8+e), [64..127] imag plane
#pragma unroll
    for (int k = 0; k < 64; ++k) lds[lane * 65 + k] = acc[k];
    __syncthreads();
    float tot = 0.f;
#pragma unroll
    for (int r = 0; r < 64; ++r) tot += lds[r * 65 + lane];
    // lane l now owns the block-total of accumulator l

    // scatter into per-slice real/imag planes via Hermitian symmetry
    if (lane < 8) {
        const int c = lane;
        fin[c * 8 + c]      = tot;   // diag re
        fin[64 + c * 8 + c] = 0.f;   // diag im = 0 exactly
    } else {
        int p = (lane < 36) ? (lane - 8) : (lane - 36);
        int c = 0;
        while (p >= 7 - c) { p -= 7 - c; ++c; }
        const int e = c + 1 + p;
        if (lane < 36) {        // real part, symmetric
            fin[c * 8 + e] = tot;
            fin[e * 8 + c] = tot;
        } else {                // imag part, antisymmetric
            fin[64 + c * 8 + e] = tot;
            fin[64 + e * 8 + c] = -tot;
        }
    }
    __syncthreads();
    out[(size_t)slice * 64 + lane] = fin[lane];                 // real plane
    if (write_imag)
        out[(size_t)real_elems + slice * 64 + lane] = fin[64 + lane];
}

extern "C" void kernel_launch(void* const* d_in, const int* in_sizes, int n_in,
                              void* d_out, int out_size, void* d_ws, size_t ws_size,
                              hipStream_t stream) {
    const float* Xr = (const float*)d_in[0];
    const float* Xi = (const float*)d_in[1];
    const float* Mk = (const float*)d_in[2];
    float* out = (float*)d_out;
    const int slices = in_sizes[2] / T_LEN;   // B*F = 2056
    const int real_elems = slices * 64;       // B*F*C*C = 131584
    const int write_imag = (out_size >= 2 * real_elems) ? 1 : 0;
    psd_kernel<<<dim3(slices), dim3(64), 0, stream>>>(Xr, Xi, Mk, out,
                                                      real_elems, write_imag);
}